// Round 6
// baseline (259.567 us; speedup 1.0000x reference)
//
#include <hip/hip_runtime.h>
#include <hip/hip_bf16.h>

// CausalSelfAttention  B=1, T=4096, C=768, H=12, hd=64
// Round 6: persistent flash w/ atomic LPT work queue (fixes 51% idle from
//          static block->work imbalance), truncating P-quantize, fused preps.
//          GEMMs + V-transpose unchanged.

#define T_SEQ 4096
#define C_DIM 768
#define C3    2304
#define NH    12
#define HD    64
#define N_ITEMS (T_SEQ / 64 * NH)  // 768

typedef __attribute__((ext_vector_type(8))) short bf16x8;
typedef __attribute__((ext_vector_type(4))) float f32x4;

__device__ inline unsigned short f2bf(float f) {
  union { float f; unsigned u; } v; v.f = f;
  unsigned r = v.u + 0x7fff + ((v.u >> 16) & 1);  // RTNE
  return (unsigned short)(r >> 16);
}
__device__ inline unsigned short f2bf_trunc(float f) {
  union { float f; unsigned u; } v; v.f = f;
  return (unsigned short)(v.u >> 16);  // truncate: fine for P in [0,1]
}
__device__ inline float bf2f(unsigned short u) {
  union { unsigned u; float f; } v; v.u = (unsigned)u << 16;
  return v.f;
}

__device__ inline void store_out(float v, float* p) { *p = v; }
__device__ inline void store_out(float v, unsigned short* p) { *p = f2bf(v); }

__device__ inline void gl2lds16(const void* g, void* l) {
  __builtin_amdgcn_global_load_lds(
      (const __attribute__((address_space(1))) unsigned int*)g,
      (__attribute__((address_space(3))) unsigned int*)l, 16, 0, 0);
}

#if __has_builtin(__builtin_amdgcn_exp2f)
#define EXP2F(x) __builtin_amdgcn_exp2f(x)
#else
#define EXP2F(x) exp2f(x)
#endif

// ---------------------------------------------------------------------------
// fused prep: conv x->bf16 | transpose w_qkv | transpose w_proj | zero counter
// ---------------------------------------------------------------------------
#define NB_CONV  (T_SEQ * C_DIM / 2048)          // 1536
#define NB_TQKV  ((C3 / 32) * (C_DIM / 32))      // 1728
#define NB_TPROJ ((C_DIM / 32) * (C_DIM / 32))   // 576

__global__ __launch_bounds__(256) void prep_fused(
    const float* __restrict__ x, const float* __restrict__ w_qkv,
    const float* __restrict__ w_proj, unsigned short* __restrict__ xb,
    unsigned short* __restrict__ wqkvT, unsigned short* __restrict__ wprojT,
    int* __restrict__ counter) {
  __shared__ float t[32][33];
  const int b = blockIdx.x;
  const int tid = threadIdx.x;
  if (b == 0 && tid == 0) *counter = 0;

  if (b < NB_CONV) {
    int i = (b * 256 + tid) * 8;
    float4 v0 = *(const float4*)(x + i);
    float4 v1 = *(const float4*)(x + i + 4);
    unsigned short o[8] = {f2bf(v0.x), f2bf(v0.y), f2bf(v0.z), f2bf(v0.w),
                           f2bf(v1.x), f2bf(v1.y), f2bf(v1.z), f2bf(v1.w)};
    *(uint4*)(xb + i) = *(uint4*)o;
    return;
  }
  const float* in;
  unsigned short* outT;
  int R, Cc, bi;
  if (b < NB_CONV + NB_TQKV) {
    in = w_qkv; outT = wqkvT; R = C_DIM; Cc = C3; bi = b - NB_CONV;
  } else {
    in = w_proj; outT = wprojT; R = C_DIM; Cc = C_DIM; bi = b - NB_CONV - NB_TQKV;
  }
  const int tx = tid & 31, ty = tid >> 5;
  const int c0 = (bi % (Cc / 32)) * 32, r0 = (bi / (Cc / 32)) * 32;
#pragma unroll
  for (int i = 0; i < 4; ++i) {
    int r = ty + i * 8;
    t[r][tx] = in[(size_t)(r0 + r) * Cc + c0 + tx];
  }
  __syncthreads();
#pragma unroll
  for (int i = 0; i < 4; ++i) {
    int c = ty + i * 8;
    outT[(size_t)(c0 + c) * R + r0 + tx] = f2bf(t[tx][c]);
  }
}

// prep: V^T — read qkv V block, write vT[768][4096] bf16 (unchanged)
__global__ __launch_bounds__(256) void transpose_v_bf16(
    const unsigned short* __restrict__ qkv, unsigned short* __restrict__ vT) {
  __shared__ unsigned short t[32][33];
  const int tx = threadIdx.x & 31, ty = threadIdx.x >> 5;
  const int c0 = blockIdx.x * 32;
  const int r0 = blockIdx.y * 32;
#pragma unroll
  for (int i = 0; i < 4; ++i) {
    int r = ty + i * 8;
    t[r][tx] = qkv[(size_t)(r0 + r) * C3 + 2 * C_DIM + c0 + tx];
  }
  __syncthreads();
#pragma unroll
  for (int i = 0; i < 4; ++i) {
    int c = ty + i * 8;
    vT[(size_t)(c0 + c) * T_SEQ + r0 + tx] = t[tx][c];
  }
}

// ---------------------------------------------------------------------------
// bf16 MFMA GEMM, B-transposed input (unchanged)
// ---------------------------------------------------------------------------
template <typename OutT>
__global__ __launch_bounds__(256) void gemm_bt_mfma(
    const unsigned short* __restrict__ A, const unsigned short* __restrict__ Bt,
    const float* __restrict__ bias, OutT* __restrict__ C,
    int M, int N, int K) {
  __shared__ unsigned short As[128 * 32];
  __shared__ unsigned short Bs[128 * 32];
  const int tid = threadIdx.x;
  const int wave = tid >> 6, lane = tid & 63;
  const int lo = lane & 15, g8 = lane >> 4;
  const int wm = wave >> 1, wn = wave & 1;
  const int bm = blockIdx.y * 128, bn = blockIdx.x * 128;
  const int lrow = lane >> 2;
  const int lcol = (lane & 3) * 8;

  f32x4 acc[4][4];
#pragma unroll
  for (int mt = 0; mt < 4; ++mt)
#pragma unroll
    for (int nt = 0; nt < 4; ++nt) acc[mt][nt] = (f32x4){0.f, 0.f, 0.f, 0.f};

  const unsigned short* Abase = A + (size_t)bm * K;
  const unsigned short* Bbase = Bt + (size_t)bn * K;

  for (int k0 = 0; k0 < K; k0 += 32) {
    __syncthreads();
#pragma unroll
    for (int c = 0; c < 2; ++c) {
      const int r = wave * 32 + c * 16;
      gl2lds16(Abase + (size_t)(r + lrow) * K + k0 + lcol, As + r * 32 + lane * 8);
      gl2lds16(Bbase + (size_t)(r + lrow) * K + k0 + lcol, Bs + r * 32 + lane * 8);
    }
    __syncthreads();

    bf16x8 a[4], b[4];
#pragma unroll
    for (int mt = 0; mt < 4; ++mt)
      a[mt] = *(const bf16x8*)(As + (wm * 64 + mt * 16 + lo) * 32 + g8 * 8);
#pragma unroll
    for (int nt = 0; nt < 4; ++nt)
      b[nt] = *(const bf16x8*)(Bs + (wn * 64 + nt * 16 + lo) * 32 + g8 * 8);
#pragma unroll
    for (int mt = 0; mt < 4; ++mt)
#pragma unroll
      for (int nt = 0; nt < 4; ++nt)
        acc[mt][nt] = __builtin_amdgcn_mfma_f32_16x16x32_bf16(a[mt], b[nt], acc[mt][nt], 0, 0, 0);
  }

#pragma unroll
  for (int nt = 0; nt < 4; ++nt) {
    const int n = bn + wn * 64 + nt * 16 + lo;
    const float bv = bias[n];
#pragma unroll
    for (int mt = 0; mt < 4; ++mt)
#pragma unroll
      for (int r = 0; r < 4; ++r) {
        const int m = bm + wm * 64 + mt * 16 + g8 * 4 + r;
        store_out(acc[mt][nt][r] + bv, &C[(size_t)m * N + n]);
      }
  }
}

// ---------------------------------------------------------------------------
// MFMA bf16 flash attention v4: persistent blocks + atomic LPT work queue.
// 768 blocks (3/CU, all resident); each grabs items (qt desc) until empty.
// XOR-swizzled K/V LDS + double-buffered DMA (from v3).
// ---------------------------------------------------------------------------
#define Q_STRIDE 72
#define P_STRIDE 72

__global__ __launch_bounds__(256) void flash_attn_mfma4(
    const unsigned short* __restrict__ qkv,   // [T][2304] bf16
    const unsigned short* __restrict__ vT,    // [768][T] bf16
    unsigned short* __restrict__ out,         // [T][768] bf16
    int* __restrict__ counter) {
  __shared__ unsigned short Qs[64 * Q_STRIDE];
  __shared__ unsigned short Ks[2][64 * 64];
  __shared__ unsigned short Vs[2][64 * 64];
  __shared__ unsigned short Ps[64 * P_STRIDE];
  __shared__ int s_item;

  const int tid = threadIdx.x;
  const int wave = tid >> 6;
  const int lane = tid & 63;
  const int lo = lane & 15;
  const int g = lane >> 4;
  const float qscale = 0.125f * 1.44269504f;  // 1/sqrt(64) * log2(e)

  const int sub = lane >> 3;
  const int slot8 = (lane & 7) * 8;
  const int csrc8 = ((lane & 7) ^ sub) * 8;
  const int sl0 = (g ^ (lo & 7)) * 8;
  const int sl1 = ((g + 4) ^ (lo & 7)) * 8;

  bf16x8 ones;
#pragma unroll
  for (int j = 0; j < 8; ++j) ones[j] = (short)0x3F80;

  for (;;) {
    if (tid == 0) s_item = atomicAdd(counter, 1);
    __syncthreads();
    const int item = s_item;
    if (item >= N_ITEMS) break;
    const int qt = 63 - item / NH;  // LPT: longest first
    const int h = item % NH;
    const int q0 = qt * 64;

    const unsigned short* Kg = qkv + C_DIM + h * HD;
    const unsigned short* Vg = vT + (size_t)(h * HD) * T_SEQ;

    // stage Q (scaled into log2 domain)
    for (int c = tid; c < 512; c += 256) {
      int r = c >> 3, ch = c & 7;
      union { uint4 v; unsigned short u[8]; } vv;
      vv.v = *(const uint4*)(qkv + (size_t)(q0 + r) * C3 + h * HD + ch * 8);
      unsigned short o[8];
#pragma unroll
      for (int j = 0; j < 8; ++j) o[j] = f2bf(bf2f(vv.u[j]) * qscale);
      *(uint4*)(Qs + r * Q_STRIDE + ch * 8) = *(uint4*)o;
    }

    // prefetch tile 0 into buffer 0
#pragma unroll
    for (int i = 0; i < 2; ++i) {
      const int rr = wave * 16 + i * 8 + sub;
      gl2lds16(Kg + (size_t)rr * C3 + csrc8, Ks[0] + rr * 64 + slot8);
      gl2lds16(Vg + (size_t)rr * T_SEQ + csrc8, Vs[0] + rr * 64 + slot8);
    }
    __syncthreads();

    bf16x8 qa0 = *(const bf16x8*)(Qs + (wave * 16 + lo) * Q_STRIDE + g * 8);
    bf16x8 qa1 = *(const bf16x8*)(Qs + (wave * 16 + lo) * Q_STRIDE + 32 + g * 8);

    float m_i[4], l_i[4];
    f32x4 o_acc[4];
#pragma unroll
    for (int r = 0; r < 4; ++r) { m_i[r] = -1e30f; l_i[r] = 0.f; }
#pragma unroll
    for (int dt = 0; dt < 4; ++dt) o_acc[dt] = (f32x4){0.f, 0.f, 0.f, 0.f};

    for (int kt = 0; kt <= qt; ++kt) {
      const int b = kt & 1;
      if (kt < qt) {
        const int k0n = (kt + 1) * 64;
#pragma unroll
        for (int i = 0; i < 2; ++i) {
          const int rr = wave * 16 + i * 8 + sub;
          gl2lds16(Kg + (size_t)(k0n + rr) * C3 + csrc8, Ks[b ^ 1] + rr * 64 + slot8);
          gl2lds16(Vg + (size_t)rr * T_SEQ + k0n + csrc8, Vs[b ^ 1] + rr * 64 + slot8);
        }
      }

      const unsigned short* Kb = Ks[b];
      const unsigned short* Vb = Vs[b];

      f32x4 s[4];
#pragma unroll
      for (int nt = 0; nt < 4; ++nt) s[nt] = (f32x4){0.f, 0.f, 0.f, 0.f};
#pragma unroll
      for (int nt = 0; nt < 4; ++nt) {
        bf16x8 kb0 = *(const bf16x8*)(Kb + (nt * 16 + lo) * 64 + sl0);
        bf16x8 kb1 = *(const bf16x8*)(Kb + (nt * 16 + lo) * 64 + sl1);
        s[nt] = __builtin_amdgcn_mfma_f32_16x16x32_bf16(qa0, kb0, s[nt], 0, 0, 0);
        s[nt] = __builtin_amdgcn_mfma_f32_16x16x32_bf16(qa1, kb1, s[nt], 0, 0, 0);
      }

      const bool diag = (kt == qt);
#pragma unroll
      for (int r = 0; r < 4; ++r) {
        float v[4];
        float mx = m_i[r];
#pragma unroll
        for (int nt = 0; nt < 4; ++nt) {
          float x = s[nt][r];
          if (diag && (nt * 16 + lo > wave * 16 + g * 4 + r)) x = -1e30f;
          v[nt] = x;
          mx = fmaxf(mx, x);
        }
#pragma unroll
        for (int off = 1; off < 16; off <<= 1) mx = fmaxf(mx, __shfl_xor(mx, off));
        const float alpha = EXP2F(m_i[r] - mx);
        m_i[r] = mx;
#pragma unroll
        for (int nt = 0; nt < 4; ++nt)
          Ps[(wave * 16 + g * 4 + r) * P_STRIDE + nt * 16 + lo] =
              f2bf_trunc(EXP2F(v[nt] - mx));
        l_i[r] *= alpha;
#pragma unroll
        for (int dt = 0; dt < 4; ++dt) o_acc[dt][r] *= alpha;
      }
      // each wave reads back only its own Ps rows — no barrier needed

      bf16x8 pa0 = *(const bf16x8*)(Ps + (wave * 16 + lo) * P_STRIDE + g * 8);
      bf16x8 pa1 = *(const bf16x8*)(Ps + (wave * 16 + lo) * P_STRIDE + 32 + g * 8);

      f32x4 lacc = (f32x4){0.f, 0.f, 0.f, 0.f};
      lacc = __builtin_amdgcn_mfma_f32_16x16x32_bf16(pa0, ones, lacc, 0, 0, 0);
      lacc = __builtin_amdgcn_mfma_f32_16x16x32_bf16(pa1, ones, lacc, 0, 0, 0);
#pragma unroll
      for (int r = 0; r < 4; ++r) l_i[r] += lacc[r];

#pragma unroll
      for (int dt = 0; dt < 4; ++dt) {
        bf16x8 vb0 = *(const bf16x8*)(Vb + (dt * 16 + lo) * 64 + sl0);
        bf16x8 vb1 = *(const bf16x8*)(Vb + (dt * 16 + lo) * 64 + sl1);
        o_acc[dt] = __builtin_amdgcn_mfma_f32_16x16x32_bf16(pa0, vb0, o_acc[dt], 0, 0, 0);
        o_acc[dt] = __builtin_amdgcn_mfma_f32_16x16x32_bf16(pa1, vb1, o_acc[dt], 0, 0, 0);
      }

      __syncthreads();  // drain next-buffer DMA + release buffer b
    }

    // epilogue (registers -> global only; next grab's barrier fences reuse)
#pragma unroll
    for (int r = 0; r < 4; ++r) {
      const float inv = 1.0f / l_i[r];
      const int row = q0 + wave * 16 + g * 4 + r;
#pragma unroll
      for (int dt = 0; dt < 4; ++dt)
        out[(size_t)row * C_DIM + h * HD + dt * 16 + lo] = f2bf(o_acc[dt][r] * inv);
    }
  }
}

// ---------------------------------------------------------------------------
extern "C" void kernel_launch(void* const* d_in, const int* in_sizes, int n_in,
                              void* d_out, int out_size, void* d_ws, size_t ws_size,
                              hipStream_t stream) {
  const float* x      = (const float*)d_in[0];
  const float* w_qkv  = (const float*)d_in[1];
  const float* b_qkv  = (const float*)d_in[2];
  const float* w_proj = (const float*)d_in[3];
  const float* b_proj = (const float*)d_in[4];
  float* out = (float*)d_out;

  int* counter = (int*)d_ws;  // 16-byte slot at head keeps arrays aligned
  unsigned short* xb     = (unsigned short*)d_ws + 8;           // [4096,768]
  unsigned short* wqkvT  = xb + (size_t)T_SEQ * C_DIM;          // [2304,768]
  unsigned short* wprojT = wqkvT + (size_t)C3 * C_DIM;          // [768,768]
  unsigned short* qkv    = wprojT + (size_t)C_DIM * C_DIM;      // [4096,2304]
  unsigned short* vT     = qkv + (size_t)T_SEQ * C3;            // [768,4096]
  unsigned short* attnb  = vT + (size_t)C_DIM * T_SEQ;          // [4096,768]

  prep_fused<<<NB_CONV + NB_TQKV + NB_TPROJ, 256, 0, stream>>>(
      x, w_qkv, w_proj, xb, wqkvT, wprojT, counter);

  gemm_bt_mfma<unsigned short><<<dim3(C3 / 128, T_SEQ / 128), 256, 0, stream>>>(
      xb, wqkvT, b_qkv, qkv, T_SEQ, C3, C_DIM);

  transpose_v_bf16<<<dim3(C_DIM / 32, T_SEQ / 32), 256, 0, stream>>>(qkv, vT);

  flash_attn_mfma4<<<N_ITEMS, 256, 0, stream>>>(qkv, vT, attnb, counter);

  gemm_bt_mfma<float><<<dim3(C_DIM / 128, T_SEQ / 128), 256, 0, stream>>>(
      attnb, wprojT, b_proj, out, T_SEQ, C_DIM, C_DIM);
}

// Round 7
// 243.989 us; speedup vs baseline: 1.0638x; 1.0638x over previous
//
#include <hip/hip_runtime.h>
#include <hip/hip_bf16.h>

// CausalSelfAttention  B=1, T=4096, C=768, H=12, hd=64
// Round 7: revert atomic queue (was a no-op: items==blocks). Flash v5:
//   software-pipelined K-loop — S(t+1) MFMAs issued before softmax(t) VALU
//   (per-wave ILP across pipes), K prefetch 2 ahead / V 1 ahead on split
//   double buffers (same 32KB LDS, 1 barrier/iter), alpha-rescale skip.

#define T_SEQ 4096
#define C_DIM 768
#define C3    2304
#define NH    12
#define HD    64

typedef __attribute__((ext_vector_type(8))) short bf16x8;
typedef __attribute__((ext_vector_type(4))) float f32x4;

__device__ inline unsigned short f2bf(float f) {
  union { float f; unsigned u; } v; v.f = f;
  unsigned r = v.u + 0x7fff + ((v.u >> 16) & 1);  // RTNE
  return (unsigned short)(r >> 16);
}
__device__ inline unsigned short f2bf_trunc(float f) {
  union { float f; unsigned u; } v; v.f = f;
  return (unsigned short)(v.u >> 16);  // truncate: fine for P in [0,1]
}
__device__ inline float bf2f(unsigned short u) {
  union { unsigned u; float f; } v; v.u = (unsigned)u << 16;
  return v.f;
}

__device__ inline void store_out(float v, float* p) { *p = v; }
__device__ inline void store_out(float v, unsigned short* p) { *p = f2bf(v); }

__device__ inline void gl2lds16(const void* g, void* l) {
  __builtin_amdgcn_global_load_lds(
      (const __attribute__((address_space(1))) unsigned int*)g,
      (__attribute__((address_space(3))) unsigned int*)l, 16, 0, 0);
}

#if __has_builtin(__builtin_amdgcn_exp2f)
#define EXP2F(x) __builtin_amdgcn_exp2f(x)
#else
#define EXP2F(x) exp2f(x)
#endif

// ---------------------------------------------------------------------------
// fused prep: conv x->bf16 | transpose w_qkv | transpose w_proj
// ---------------------------------------------------------------------------
#define NB_CONV  (T_SEQ * C_DIM / 2048)          // 1536
#define NB_TQKV  ((C3 / 32) * (C_DIM / 32))      // 1728
#define NB_TPROJ ((C_DIM / 32) * (C_DIM / 32))   // 576

__global__ __launch_bounds__(256) void prep_fused(
    const float* __restrict__ x, const float* __restrict__ w_qkv,
    const float* __restrict__ w_proj, unsigned short* __restrict__ xb,
    unsigned short* __restrict__ wqkvT, unsigned short* __restrict__ wprojT) {
  __shared__ float t[32][33];
  const int b = blockIdx.x;
  const int tid = threadIdx.x;

  if (b < NB_CONV) {
    int i = (b * 256 + tid) * 8;
    float4 v0 = *(const float4*)(x + i);
    float4 v1 = *(const float4*)(x + i + 4);
    unsigned short o[8] = {f2bf(v0.x), f2bf(v0.y), f2bf(v0.z), f2bf(v0.w),
                           f2bf(v1.x), f2bf(v1.y), f2bf(v1.z), f2bf(v1.w)};
    *(uint4*)(xb + i) = *(uint4*)o;
    return;
  }
  const float* in;
  unsigned short* outT;
  int R, Cc, bi;
  if (b < NB_CONV + NB_TQKV) {
    in = w_qkv; outT = wqkvT; R = C_DIM; Cc = C3; bi = b - NB_CONV;
  } else {
    in = w_proj; outT = wprojT; R = C_DIM; Cc = C_DIM; bi = b - NB_CONV - NB_TQKV;
  }
  const int tx = tid & 31, ty = tid >> 5;
  const int c0 = (bi % (Cc / 32)) * 32, r0 = (bi / (Cc / 32)) * 32;
#pragma unroll
  for (int i = 0; i < 4; ++i) {
    int r = ty + i * 8;
    t[r][tx] = in[(size_t)(r0 + r) * Cc + c0 + tx];
  }
  __syncthreads();
#pragma unroll
  for (int i = 0; i < 4; ++i) {
    int c = ty + i * 8;
    outT[(size_t)(c0 + c) * R + r0 + tx] = f2bf(t[tx][c]);
  }
}

// prep: V^T — read qkv V block, write vT[768][4096] bf16
__global__ __launch_bounds__(256) void transpose_v_bf16(
    const unsigned short* __restrict__ qkv, unsigned short* __restrict__ vT) {
  __shared__ unsigned short t[32][33];
  const int tx = threadIdx.x & 31, ty = threadIdx.x >> 5;
  const int c0 = blockIdx.x * 32;
  const int r0 = blockIdx.y * 32;
#pragma unroll
  for (int i = 0; i < 4; ++i) {
    int r = ty + i * 8;
    t[r][tx] = qkv[(size_t)(r0 + r) * C3 + 2 * C_DIM + c0 + tx];
  }
  __syncthreads();
#pragma unroll
  for (int i = 0; i < 4; ++i) {
    int c = ty + i * 8;
    vT[(size_t)(c0 + c) * T_SEQ + r0 + tx] = t[tx][c];
  }
}

// ---------------------------------------------------------------------------
// bf16 MFMA GEMM, B-transposed input (unchanged)
// ---------------------------------------------------------------------------
template <typename OutT>
__global__ __launch_bounds__(256) void gemm_bt_mfma(
    const unsigned short* __restrict__ A, const unsigned short* __restrict__ Bt,
    const float* __restrict__ bias, OutT* __restrict__ C,
    int M, int N, int K) {
  __shared__ unsigned short As[128 * 32];
  __shared__ unsigned short Bs[128 * 32];
  const int tid = threadIdx.x;
  const int wave = tid >> 6, lane = tid & 63;
  const int lo = lane & 15, g8 = lane >> 4;
  const int wm = wave >> 1, wn = wave & 1;
  const int bm = blockIdx.y * 128, bn = blockIdx.x * 128;
  const int lrow = lane >> 2;
  const int lcol = (lane & 3) * 8;

  f32x4 acc[4][4];
#pragma unroll
  for (int mt = 0; mt < 4; ++mt)
#pragma unroll
    for (int nt = 0; nt < 4; ++nt) acc[mt][nt] = (f32x4){0.f, 0.f, 0.f, 0.f};

  const unsigned short* Abase = A + (size_t)bm * K;
  const unsigned short* Bbase = Bt + (size_t)bn * K;

  for (int k0 = 0; k0 < K; k0 += 32) {
    __syncthreads();
#pragma unroll
    for (int c = 0; c < 2; ++c) {
      const int r = wave * 32 + c * 16;
      gl2lds16(Abase + (size_t)(r + lrow) * K + k0 + lcol, As + r * 32 + lane * 8);
      gl2lds16(Bbase + (size_t)(r + lrow) * K + k0 + lcol, Bs + r * 32 + lane * 8);
    }
    __syncthreads();

    bf16x8 a[4], b[4];
#pragma unroll
    for (int mt = 0; mt < 4; ++mt)
      a[mt] = *(const bf16x8*)(As + (wm * 64 + mt * 16 + lo) * 32 + g8 * 8);
#pragma unroll
    for (int nt = 0; nt < 4; ++nt)
      b[nt] = *(const bf16x8*)(Bs + (wn * 64 + nt * 16 + lo) * 32 + g8 * 8);
#pragma unroll
    for (int mt = 0; mt < 4; ++mt)
#pragma unroll
      for (int nt = 0; nt < 4; ++nt)
        acc[mt][nt] = __builtin_amdgcn_mfma_f32_16x16x32_bf16(a[mt], b[nt], acc[mt][nt], 0, 0, 0);
  }

#pragma unroll
  for (int nt = 0; nt < 4; ++nt) {
    const int n = bn + wn * 64 + nt * 16 + lo;
    const float bv = bias[n];
#pragma unroll
    for (int mt = 0; mt < 4; ++mt)
#pragma unroll
      for (int r = 0; r < 4; ++r) {
        const int m = bm + wm * 64 + mt * 16 + g8 * 4 + r;
        store_out(acc[mt][nt][r] + bv, &C[(size_t)m * N + n]);
      }
  }
}

// ---------------------------------------------------------------------------
// MFMA bf16 flash attention v5: software-pipelined K-loop.
// Static LPT grid (768 blocks): qt = 63 - blockIdx.x/12, h = blockIdx.x%12.
// Buffer schedule (verified hazard-free, 1 barrier/iter):
//   iter t: K-DMA(t+2)->Ks[t&1]   (K[t] dead since iter t-1, fenced B_{t-1})
//           V-DMA(t+1)->Vs[(t+1)&1] (V[t-1] dead since iter t-1)
//           S(t+1) = QK(Ks[(t+1)&1])  (K[t+1] DMA'd iter t-1, drained B_{t-1})
//           softmax(t) on S(t) from prev iter; PV(t) via Vs[t&1]; barrier B_t.
// Prologue: DMA K0,V0,K1; barrier; S0; barrier (fences S0's Ks[0] reads).
// ---------------------------------------------------------------------------
#define Q_STRIDE 72
#define P_STRIDE 72

__global__ __launch_bounds__(256) void flash_attn_mfma5(
    const unsigned short* __restrict__ qkv,   // [T][2304] bf16
    const unsigned short* __restrict__ vT,    // [768][T] bf16
    unsigned short* __restrict__ out) {       // [T][768] bf16
  __shared__ unsigned short Qs[64 * Q_STRIDE];
  __shared__ unsigned short Ks[2][64 * 64];   // swizzled
  __shared__ unsigned short Vs[2][64 * 64];   // swizzled
  __shared__ unsigned short Ps[64 * P_STRIDE];

  const int qt = 63 - blockIdx.x / NH;  // static LPT
  const int h = blockIdx.x % NH;
  const int q0 = qt * 64;
  const int tid = threadIdx.x;
  const int wave = tid >> 6;
  const int lane = tid & 63;
  const int lo = lane & 15;
  const int g = lane >> 4;
  const float qscale = 0.125f * 1.44269504f;  // 1/sqrt(64) * log2(e)

  const unsigned short* Kg = qkv + C_DIM + h * HD;          // row stride C3
  const unsigned short* Vg = vT + (size_t)(h * HD) * T_SEQ; // row stride T_SEQ
  const int sub = lane >> 3;
  const int slot8 = (lane & 7) * 8;
  const int csrc8 = ((lane & 7) ^ sub) * 8;
  const int sl0 = (g ^ (lo & 7)) * 8;
  const int sl1 = ((g + 4) ^ (lo & 7)) * 8;

  // stage Q (scaled into log2 domain)
  for (int c = tid; c < 512; c += 256) {
    int r = c >> 3, ch = c & 7;
    union { uint4 v; unsigned short u[8]; } vv;
    vv.v = *(const uint4*)(qkv + (size_t)(q0 + r) * C3 + h * HD + ch * 8);
    unsigned short o[8];
#pragma unroll
    for (int j = 0; j < 8; ++j) o[j] = f2bf(bf2f(vv.u[j]) * qscale);
    *(uint4*)(Qs + r * Q_STRIDE + ch * 8) = *(uint4*)o;
  }

  // prologue DMAs: K0, V0, (K1)
  {
    const int rr = wave * 16 + sub;
#pragma unroll
    for (int i = 0; i < 2; ++i) {
      const int r2 = rr + i * 8;
      gl2lds16(Kg + (size_t)r2 * C3 + csrc8, Ks[0] + r2 * 64 + slot8);
      gl2lds16(Vg + (size_t)r2 * T_SEQ + csrc8, Vs[0] + r2 * 64 + slot8);
      if (qt >= 1)
        gl2lds16(Kg + (size_t)(64 + r2) * C3 + csrc8, Ks[1] + r2 * 64 + slot8);
    }
  }
  __syncthreads();  // drains prologue DMAs; Qs visible

  bf16x8 qa0 = *(const bf16x8*)(Qs + (wave * 16 + lo) * Q_STRIDE + g * 8);
  bf16x8 qa1 = *(const bf16x8*)(Qs + (wave * 16 + lo) * Q_STRIDE + 32 + g * 8);

  bf16x8 ones;
#pragma unroll
  for (int j = 0; j < 8; ++j) ones[j] = (short)0x3F80;

  float m_i[4], l_i[4];
  f32x4 o_acc[4];
#pragma unroll
  for (int r = 0; r < 4; ++r) { m_i[r] = -1e30f; l_i[r] = 0.f; }
#pragma unroll
  for (int dt = 0; dt < 4; ++dt) o_acc[dt] = (f32x4){0.f, 0.f, 0.f, 0.f};

  // S0 in prologue
  f32x4 s_cur[4];
#pragma unroll
  for (int nt = 0; nt < 4; ++nt) s_cur[nt] = (f32x4){0.f, 0.f, 0.f, 0.f};
#pragma unroll
  for (int nt = 0; nt < 4; ++nt) {
    bf16x8 kb0 = *(const bf16x8*)(Ks[0] + (nt * 16 + lo) * 64 + sl0);
    bf16x8 kb1 = *(const bf16x8*)(Ks[0] + (nt * 16 + lo) * 64 + sl1);
    s_cur[nt] = __builtin_amdgcn_mfma_f32_16x16x32_bf16(qa0, kb0, s_cur[nt], 0, 0, 0);
    s_cur[nt] = __builtin_amdgcn_mfma_f32_16x16x32_bf16(qa1, kb1, s_cur[nt], 0, 0, 0);
  }
  __syncthreads();  // fences all waves' S0 reads of Ks[0] (iter0 overwrites it)

  for (int t = 0; t <= qt; ++t) {
    const int cur = t & 1;
    // prefetch: K two ahead, V one ahead
    if (t + 2 <= qt) {
      const int k0n = (t + 2) * 64;
#pragma unroll
      for (int i = 0; i < 2; ++i) {
        const int rr = wave * 16 + i * 8 + sub;
        gl2lds16(Kg + (size_t)(k0n + rr) * C3 + csrc8, Ks[cur] + rr * 64 + slot8);
      }
    }
    if (t + 1 <= qt) {
      const int k0v = (t + 1) * 64;
#pragma unroll
      for (int i = 0; i < 2; ++i) {
        const int rr = wave * 16 + i * 8 + sub;
        gl2lds16(Vg + (size_t)rr * T_SEQ + k0v + csrc8, Vs[cur ^ 1] + rr * 64 + slot8);
      }
    }

    // S(t+1) early — independent MFMAs overlap softmax(t) VALU below
    f32x4 s_nxt[4];
    if (t + 1 <= qt) {
#pragma unroll
      for (int nt = 0; nt < 4; ++nt) s_nxt[nt] = (f32x4){0.f, 0.f, 0.f, 0.f};
      const unsigned short* Kb = Ks[cur ^ 1];
#pragma unroll
      for (int nt = 0; nt < 4; ++nt) {
        bf16x8 kb0 = *(const bf16x8*)(Kb + (nt * 16 + lo) * 64 + sl0);
        bf16x8 kb1 = *(const bf16x8*)(Kb + (nt * 16 + lo) * 64 + sl1);
        s_nxt[nt] = __builtin_amdgcn_mfma_f32_16x16x32_bf16(qa0, kb0, s_nxt[nt], 0, 0, 0);
        s_nxt[nt] = __builtin_amdgcn_mfma_f32_16x16x32_bf16(qa1, kb1, s_nxt[nt], 0, 0, 0);
      }
    }

    // softmax(t) on s_cur
    const bool diag = (t == qt);
#pragma unroll
    for (int r = 0; r < 4; ++r) {
      float v[4];
      float mx = m_i[r];
#pragma unroll
      for (int nt = 0; nt < 4; ++nt) {
        float x = s_cur[nt][r];
        if (diag && (nt * 16 + lo > wave * 16 + g * 4 + r)) x = -1e30f;
        v[nt] = x;
        mx = fmaxf(mx, x);
      }
#pragma unroll
      for (int off = 1; off < 16; off <<= 1) mx = fmaxf(mx, __shfl_xor(mx, off));
      const float alpha = EXP2F(m_i[r] - mx);
      m_i[r] = mx;
#pragma unroll
      for (int nt = 0; nt < 4; ++nt)
        Ps[(wave * 16 + g * 4 + r) * P_STRIDE + nt * 16 + lo] =
            f2bf_trunc(EXP2F(v[nt] - mx));
      if (__any(alpha != 1.0f)) {  // skip rescale once max has settled
        l_i[r] *= alpha;
#pragma unroll
        for (int dt = 0; dt < 4; ++dt) o_acc[dt][r] *= alpha;
      }
    }
    // each wave reads back only its own Ps rows — no barrier needed

    bf16x8 pa0 = *(const bf16x8*)(Ps + (wave * 16 + lo) * P_STRIDE + g * 8);
    bf16x8 pa1 = *(const bf16x8*)(Ps + (wave * 16 + lo) * P_STRIDE + 32 + g * 8);

    f32x4 lacc = (f32x4){0.f, 0.f, 0.f, 0.f};
    lacc = __builtin_amdgcn_mfma_f32_16x16x32_bf16(pa0, ones, lacc, 0, 0, 0);
    lacc = __builtin_amdgcn_mfma_f32_16x16x32_bf16(pa1, ones, lacc, 0, 0, 0);
#pragma unroll
    for (int r = 0; r < 4; ++r) l_i[r] += lacc[r];

    const unsigned short* Vb = Vs[cur];
#pragma unroll
    for (int dt = 0; dt < 4; ++dt) {
      bf16x8 vb0 = *(const bf16x8*)(Vb + (dt * 16 + lo) * 64 + sl0);
      bf16x8 vb1 = *(const bf16x8*)(Vb + (dt * 16 + lo) * 64 + sl1);
      o_acc[dt] = __builtin_amdgcn_mfma_f32_16x16x32_bf16(pa0, vb0, o_acc[dt], 0, 0, 0);
      o_acc[dt] = __builtin_amdgcn_mfma_f32_16x16x32_bf16(pa1, vb1, o_acc[dt], 0, 0, 0);
    }

#pragma unroll
    for (int nt = 0; nt < 4; ++nt) s_cur[nt] = s_nxt[nt];

    __syncthreads();  // B_t: drains this iter's DMAs, fences buffer reuse
  }

#pragma unroll
  for (int r = 0; r < 4; ++r) {
    const float inv = 1.0f / l_i[r];
    const int row = q0 + wave * 16 + g * 4 + r;
#pragma unroll
    for (int dt = 0; dt < 4; ++dt)
      out[(size_t)row * C_DIM + h * HD + dt * 16 + lo] = f2bf(o_acc[dt][r] * inv);
  }
}

// ---------------------------------------------------------------------------
extern "C" void kernel_launch(void* const* d_in, const int* in_sizes, int n_in,
                              void* d_out, int out_size, void* d_ws, size_t ws_size,
                              hipStream_t stream) {
  const float* x      = (const float*)d_in[0];
  const float* w_qkv  = (const float*)d_in[1];
  const float* b_qkv  = (const float*)d_in[2];
  const float* w_proj = (const float*)d_in[3];
  const float* b_proj = (const float*)d_in[4];
  float* out = (float*)d_out;

  unsigned short* xb     = (unsigned short*)d_ws;               // [4096,768]
  unsigned short* wqkvT  = xb + (size_t)T_SEQ * C_DIM;          // [2304,768]
  unsigned short* wprojT = wqkvT + (size_t)C3 * C_DIM;          // [768,768]
  unsigned short* qkv    = wprojT + (size_t)C_DIM * C_DIM;      // [4096,2304]
  unsigned short* vT     = qkv + (size_t)T_SEQ * C3;            // [768,4096]
  unsigned short* attnb  = vT + (size_t)C_DIM * T_SEQ;          // [4096,768]

  prep_fused<<<NB_CONV + NB_TQKV + NB_TPROJ, 256, 0, stream>>>(
      x, w_qkv, w_proj, xb, wqkvT, wprojT);

  gemm_bt_mfma<unsigned short><<<dim3(C3 / 128, T_SEQ / 128), 256, 0, stream>>>(
      xb, wqkvT, b_qkv, qkv, T_SEQ, C3, C_DIM);

  transpose_v_bf16<<<dim3(C_DIM / 32, T_SEQ / 32), 256, 0, stream>>>(qkv, vT);

  flash_attn_mfma5<<<T_SEQ / 64 * NH, 256, 0, stream>>>(qkv, vT, attnb);

  gemm_bt_mfma<float><<<dim3(C_DIM / 128, T_SEQ / 128), 256, 0, stream>>>(
      attnb, wprojT, b_proj, out, T_SEQ, C_DIM, C_DIM);
}

// Round 8
// 232.225 us; speedup vs baseline: 1.1177x; 1.0507x over previous
//
#include <hip/hip_runtime.h>
#include <hip/hip_bf16.h>

// CausalSelfAttention  B=1, T=4096, C=768, H=12, hd=64
// Round 8: flash v6 — transposed-S (St = K@Q^T): in-register softmax
//   (2 shfls), P never touches LDS (C-frag -> B-operand via logical-k
//   permutation mirrored on V^T A-frags), Q frags direct from global,
//   LDS = K/V double-buffer only (32KB), 128-thread blocks.
//   GEMMs/preps unchanged.

#define T_SEQ 4096
#define C_DIM 768
#define C3    2304
#define NH    12
#define HD    64

typedef __attribute__((ext_vector_type(8))) short bf16x8;
typedef __attribute__((ext_vector_type(4))) short bf16x4;
typedef __attribute__((ext_vector_type(4))) float f32x4;

__device__ inline unsigned short f2bf(float f) {
  union { float f; unsigned u; } v; v.f = f;
  unsigned r = v.u + 0x7fff + ((v.u >> 16) & 1);  // RTNE
  return (unsigned short)(r >> 16);
}
__device__ inline unsigned short f2bf_trunc(float f) {
  union { float f; unsigned u; } v; v.f = f;
  return (unsigned short)(v.u >> 16);  // truncate: fine for P in [0,1]
}

__device__ inline void store_out(float v, float* p) { *p = v; }
__device__ inline void store_out(float v, unsigned short* p) { *p = f2bf(v); }

__device__ inline void gl2lds16(const void* g, void* l) {
  __builtin_amdgcn_global_load_lds(
      (const __attribute__((address_space(1))) unsigned int*)g,
      (__attribute__((address_space(3))) unsigned int*)l, 16, 0, 0);
}

#if __has_builtin(__builtin_amdgcn_exp2f)
#define EXP2F(x) __builtin_amdgcn_exp2f(x)
#else
#define EXP2F(x) exp2f(x)
#endif

// ---------------------------------------------------------------------------
// fused prep: conv x->bf16 | transpose w_qkv | transpose w_proj
// ---------------------------------------------------------------------------
#define NB_CONV  (T_SEQ * C_DIM / 2048)          // 1536
#define NB_TQKV  ((C3 / 32) * (C_DIM / 32))      // 1728
#define NB_TPROJ ((C_DIM / 32) * (C_DIM / 32))   // 576

__global__ __launch_bounds__(256) void prep_fused(
    const float* __restrict__ x, const float* __restrict__ w_qkv,
    const float* __restrict__ w_proj, unsigned short* __restrict__ xb,
    unsigned short* __restrict__ wqkvT, unsigned short* __restrict__ wprojT) {
  __shared__ float t[32][33];
  const int b = blockIdx.x;
  const int tid = threadIdx.x;

  if (b < NB_CONV) {
    int i = (b * 256 + tid) * 8;
    float4 v0 = *(const float4*)(x + i);
    float4 v1 = *(const float4*)(x + i + 4);
    unsigned short o[8] = {f2bf(v0.x), f2bf(v0.y), f2bf(v0.z), f2bf(v0.w),
                           f2bf(v1.x), f2bf(v1.y), f2bf(v1.z), f2bf(v1.w)};
    *(uint4*)(xb + i) = *(uint4*)o;
    return;
  }
  const float* in;
  unsigned short* outT;
  int R, Cc, bi;
  if (b < NB_CONV + NB_TQKV) {
    in = w_qkv; outT = wqkvT; R = C_DIM; Cc = C3; bi = b - NB_CONV;
  } else {
    in = w_proj; outT = wprojT; R = C_DIM; Cc = C_DIM; bi = b - NB_CONV - NB_TQKV;
  }
  const int tx = tid & 31, ty = tid >> 5;
  const int c0 = (bi % (Cc / 32)) * 32, r0 = (bi / (Cc / 32)) * 32;
#pragma unroll
  for (int i = 0; i < 4; ++i) {
    int r = ty + i * 8;
    t[r][tx] = in[(size_t)(r0 + r) * Cc + c0 + tx];
  }
  __syncthreads();
#pragma unroll
  for (int i = 0; i < 4; ++i) {
    int c = ty + i * 8;
    outT[(size_t)(c0 + c) * R + r0 + tx] = f2bf(t[tx][c]);
  }
}

// prep: V^T — read qkv V block, write vT[768][4096] bf16
__global__ __launch_bounds__(256) void transpose_v_bf16(
    const unsigned short* __restrict__ qkv, unsigned short* __restrict__ vT) {
  __shared__ unsigned short t[32][33];
  const int tx = threadIdx.x & 31, ty = threadIdx.x >> 5;
  const int c0 = blockIdx.x * 32;
  const int r0 = blockIdx.y * 32;
#pragma unroll
  for (int i = 0; i < 4; ++i) {
    int r = ty + i * 8;
    t[r][tx] = qkv[(size_t)(r0 + r) * C3 + 2 * C_DIM + c0 + tx];
  }
  __syncthreads();
#pragma unroll
  for (int i = 0; i < 4; ++i) {
    int c = ty + i * 8;
    vT[(size_t)(c0 + c) * T_SEQ + r0 + tx] = t[tx][c];
  }
}

// ---------------------------------------------------------------------------
// bf16 MFMA GEMM, B-transposed input (unchanged)
// ---------------------------------------------------------------------------
template <typename OutT>
__global__ __launch_bounds__(256) void gemm_bt_mfma(
    const unsigned short* __restrict__ A, const unsigned short* __restrict__ Bt,
    const float* __restrict__ bias, OutT* __restrict__ C,
    int M, int N, int K) {
  __shared__ unsigned short As[128 * 32];
  __shared__ unsigned short Bs[128 * 32];
  const int tid = threadIdx.x;
  const int wave = tid >> 6, lane = tid & 63;
  const int lo = lane & 15, g8 = lane >> 4;
  const int wm = wave >> 1, wn = wave & 1;
  const int bm = blockIdx.y * 128, bn = blockIdx.x * 128;
  const int lrow = lane >> 2;
  const int lcol = (lane & 3) * 8;

  f32x4 acc[4][4];
#pragma unroll
  for (int mt = 0; mt < 4; ++mt)
#pragma unroll
    for (int nt = 0; nt < 4; ++nt) acc[mt][nt] = (f32x4){0.f, 0.f, 0.f, 0.f};

  const unsigned short* Abase = A + (size_t)bm * K;
  const unsigned short* Bbase = Bt + (size_t)bn * K;

  for (int k0 = 0; k0 < K; k0 += 32) {
    __syncthreads();
#pragma unroll
    for (int c = 0; c < 2; ++c) {
      const int r = wave * 32 + c * 16;
      gl2lds16(Abase + (size_t)(r + lrow) * K + k0 + lcol, As + r * 32 + lane * 8);
      gl2lds16(Bbase + (size_t)(r + lrow) * K + k0 + lcol, Bs + r * 32 + lane * 8);
    }
    __syncthreads();

    bf16x8 a[4], b[4];
#pragma unroll
    for (int mt = 0; mt < 4; ++mt)
      a[mt] = *(const bf16x8*)(As + (wm * 64 + mt * 16 + lo) * 32 + g8 * 8);
#pragma unroll
    for (int nt = 0; nt < 4; ++nt)
      b[nt] = *(const bf16x8*)(Bs + (wn * 64 + nt * 16 + lo) * 32 + g8 * 8);
#pragma unroll
    for (int mt = 0; mt < 4; ++mt)
#pragma unroll
      for (int nt = 0; nt < 4; ++nt)
        acc[mt][nt] = __builtin_amdgcn_mfma_f32_16x16x32_bf16(a[mt], b[nt], acc[mt][nt], 0, 0, 0);
  }

#pragma unroll
  for (int nt = 0; nt < 4; ++nt) {
    const int n = bn + wn * 64 + nt * 16 + lo;
    const float bv = bias[n];
#pragma unroll
    for (int mt = 0; mt < 4; ++mt)
#pragma unroll
      for (int r = 0; r < 4; ++r) {
        const int m = bm + wm * 64 + mt * 16 + g8 * 4 + r;
        store_out(acc[mt][nt][r] + bv, &C[(size_t)m * N + n]);
      }
  }
}

// ---------------------------------------------------------------------------
// flash v6: St = K@Q^T, in-register softmax, LDS-free P, 128-thr blocks.
// grid 768 LPT (qt = 63 - b/12). Wave w owns q-cols [w*32, w*32+32) (nt=2).
// St C-frag: col=lo=q, row=g*4+r=k (within mt*16). Softmax per q-col:
//   in-lane max/sum over 16 vals + shfl_xor(16,32) over g-replicas.
// PV: O^T[d][q] = V^T @ P^T via x32 MFMA under logical-k permutation
//   pi(8g+i) = kh*32 + (i<4 ? 4g+i : 16+4g+i-4), applied to BOTH operands.
// ---------------------------------------------------------------------------
__global__ __launch_bounds__(128) void flash_attn_mfma6(
    const unsigned short* __restrict__ qkv,   // [T][2304] bf16
    const unsigned short* __restrict__ vT,    // [768][T] bf16
    unsigned short* __restrict__ out) {       // [T][768] bf16
  __shared__ unsigned short Ks[2][64 * 64];   // [k][d] chunk-swizzled
  __shared__ unsigned short Vs[2][64 * 64];   // [d][k] chunk-swizzled

  const int qt = 63 - blockIdx.x / NH;  // LPT
  const int h = blockIdx.x % NH;
  const int q0 = qt * 64;
  const int tid = threadIdx.x;
  const int w = tid >> 6;
  const int lane = tid & 63;
  const int lo = lane & 15;
  const int g = lane >> 4;
  const float qscale = 0.125f * 1.44269504f;  // 1/sqrt(64) * log2(e)

  const unsigned short* Kg = qkv + C_DIM + h * HD;          // row stride C3
  const unsigned short* Vg = vT + (size_t)(h * HD) * T_SEQ; // row stride T_SEQ

  // DMA mapping: 128 threads x 4 passes cover 64 rows x 8 chunks (swizzled)
  const int drow = tid >> 3;                    // 0..15
  const int dslot = (tid & 7) * 8;
  const int dsrc = ((tid & 7) ^ (drow & 7)) * 8;

  // Q B-frags direct from global (one-time, uncoalesced but tiny)
  bf16x8 qb[2][2];
#pragma unroll
  for (int nt = 0; nt < 2; ++nt)
#pragma unroll
    for (int dh = 0; dh < 2; ++dh)
      qb[nt][dh] = *(const bf16x8*)(
          qkv + (size_t)(q0 + w * 32 + nt * 16 + lo) * C3 + h * HD + dh * 32 + g * 8);

  // prologue: DMA K0, V0
#pragma unroll
  for (int p = 0; p < 4; ++p) {
    const int r = p * 16 + drow;
    gl2lds16(Kg + (size_t)r * C3 + dsrc, Ks[0] + r * 64 + dslot);
    gl2lds16(Vg + (size_t)r * T_SEQ + dsrc, Vs[0] + r * 64 + dslot);
  }
  __syncthreads();

  float m_i[2] = {-1e30f, -1e30f}, l_i[2] = {0.f, 0.f};
  f32x4 o_acc[2][4];
#pragma unroll
  for (int nt = 0; nt < 2; ++nt)
#pragma unroll
    for (int dt = 0; dt < 4; ++dt) o_acc[nt][dt] = (f32x4){0.f, 0.f, 0.f, 0.f};

  const int lo7 = lo & 7;

  for (int t = 0; t <= qt; ++t) {
    const int cur = t & 1;
    if (t < qt) {
      const int k0n = (t + 1) * 64;
#pragma unroll
      for (int p = 0; p < 4; ++p) {
        const int r = p * 16 + drow;
        gl2lds16(Kg + (size_t)(k0n + r) * C3 + dsrc, Ks[cur ^ 1] + r * 64 + dslot);
        gl2lds16(Vg + (size_t)r * T_SEQ + k0n + dsrc, Vs[cur ^ 1] + r * 64 + dslot);
      }
    }

    // St = K @ Q^T : A = K-frags (8 reads, shared across nt)
    bf16x8 a[4][2];
#pragma unroll
    for (int mt = 0; mt < 4; ++mt)
#pragma unroll
      for (int dh = 0; dh < 2; ++dh)
        a[mt][dh] = *(const bf16x8*)(
            Ks[cur] + (mt * 16 + lo) * 64 + (((dh * 4 + g) ^ lo7) * 8));

    f32x4 st[2][4];
#pragma unroll
    for (int nt = 0; nt < 2; ++nt)
#pragma unroll
      for (int mt = 0; mt < 4; ++mt) st[nt][mt] = (f32x4){0.f, 0.f, 0.f, 0.f};
#pragma unroll
    for (int nt = 0; nt < 2; ++nt)
#pragma unroll
      for (int mt = 0; mt < 4; ++mt)
#pragma unroll
        for (int dh = 0; dh < 2; ++dh)
          st[nt][mt] = __builtin_amdgcn_mfma_f32_16x16x32_bf16(
              a[mt][dh], qb[nt][dh], st[nt][mt], 0, 0, 0);

    // softmax (raw domain; scale folded into exp2)
    const bool diag = (t == qt);
    bf16x8 pt[2][2];
#pragma unroll
    for (int nt = 0; nt < 2; ++nt) {
      const int qloc = w * 32 + nt * 16 + lo;
      if (diag) {
#pragma unroll
        for (int mt = 0; mt < 4; ++mt)
#pragma unroll
          for (int r = 0; r < 4; ++r)
            if (mt * 16 + g * 4 + r > qloc) st[nt][mt][r] = -1e30f;
      }
      float mx = -1e30f;
#pragma unroll
      for (int mt = 0; mt < 4; ++mt)
#pragma unroll
        for (int r = 0; r < 4; ++r) mx = fmaxf(mx, st[nt][mt][r]);
      mx = fmaxf(mx, __shfl_xor(mx, 16));
      mx = fmaxf(mx, __shfl_xor(mx, 32));
      const float mnew = fmaxf(m_i[nt], mx);
      const float alpha = EXP2F((m_i[nt] - mnew) * qscale);
      m_i[nt] = mnew;
      const float ms = mnew * qscale;
      float e[4][4];
      float lsum = 0.f;
#pragma unroll
      for (int mt = 0; mt < 4; ++mt)
#pragma unroll
        for (int r = 0; r < 4; ++r) {
          float v = EXP2F(__builtin_fmaf(st[nt][mt][r], qscale, -ms));
          e[mt][r] = v;
          lsum += v;
        }
      lsum += __shfl_xor(lsum, 16);
      lsum += __shfl_xor(lsum, 32);
#pragma unroll
      for (int kh = 0; kh < 2; ++kh) {
        bf16x8 p8;
#pragma unroll
        for (int j = 0; j < 4; ++j) {
          p8[j] = (short)f2bf_trunc(e[kh * 2][j]);
          p8[4 + j] = (short)f2bf_trunc(e[kh * 2 + 1][j]);
        }
        pt[nt][kh] = p8;
      }
      if (__any(alpha != 1.0f)) {
        l_i[nt] *= alpha;
#pragma unroll
        for (int dt = 0; dt < 4; ++dt) {
#pragma unroll
          for (int r = 0; r < 4; ++r) o_acc[nt][dt][r] *= alpha;
        }
      }
      l_i[nt] += lsum;
    }

    // O^T += V^T @ P^T (permuted-k x32; A-frags shared across nt)
#pragma unroll
    for (int dt = 0; dt < 4; ++dt) {
      const int vrow = (dt * 16 + lo) * 64 + 4 * (g & 1);
#pragma unroll
      for (int kh = 0; kh < 2; ++kh) {
        const int sA = (kh * 4 + (g >> 1)) ^ lo7;
        const int sB = (kh * 4 + 2 + (g >> 1)) ^ lo7;
        bf16x4 v0 = *(const bf16x4*)(Vs[cur] + vrow + sA * 8);
        bf16x4 v1 = *(const bf16x4*)(Vs[cur] + vrow + sB * 8);
        bf16x8 av;
#pragma unroll
        for (int j = 0; j < 4; ++j) { av[j] = v0[j]; av[4 + j] = v1[j]; }
#pragma unroll
        for (int nt = 0; nt < 2; ++nt)
          o_acc[nt][dt] = __builtin_amdgcn_mfma_f32_16x16x32_bf16(
              av, pt[nt][kh], o_acc[nt][dt], 0, 0, 0);
      }
    }

    __syncthreads();  // drain prefetch DMAs + release buffer cur
  }

  // epilogue: O^T frags -> Ks[0] (swizzled, wave-local rows) -> coalesced out
#pragma unroll
  for (int nt = 0; nt < 2; ++nt) {
    const float inv = 1.0f / l_i[nt];
    const int qloc = w * 32 + nt * 16 + lo;
#pragma unroll
    for (int dt = 0; dt < 4; ++dt) {
      const int chunk = (dt * 2 + (g >> 1)) ^ lo7;
#pragma unroll
      for (int r = 0; r < 4; ++r)
        Ks[0][qloc * 64 + chunk * 8 + 4 * (g & 1) + r] =
            f2bf(o_acc[nt][dt][r] * inv);
    }
  }
  // same-wave readback (rows disjoint per wave; lgkmcnt orders within wave)
#pragma unroll
  for (int i = 0; i < 4; ++i) {
    const int row = w * 32 + i * 8 + (lane >> 3);
    bf16x8 val = *(const bf16x8*)(Ks[0] + row * 64 + (((lane & 7) ^ (lane >> 3)) * 8));
    *(bf16x8*)(out + (size_t)(q0 + row) * C_DIM + h * HD + (lane & 7) * 8) = val;
  }
}

// ---------------------------------------------------------------------------
extern "C" void kernel_launch(void* const* d_in, const int* in_sizes, int n_in,
                              void* d_out, int out_size, void* d_ws, size_t ws_size,
                              hipStream_t stream) {
  const float* x      = (const float*)d_in[0];
  const float* w_qkv  = (const float*)d_in[1];
  const float* b_qkv  = (const float*)d_in[2];
  const float* w_proj = (const float*)d_in[3];
  const float* b_proj = (const float*)d_in[4];
  float* out = (float*)d_out;

  unsigned short* xb     = (unsigned short*)d_ws;               // [4096,768]
  unsigned short* wqkvT  = xb + (size_t)T_SEQ * C_DIM;          // [2304,768]
  unsigned short* wprojT = wqkvT + (size_t)C3 * C_DIM;          // [768,768]
  unsigned short* qkv    = wprojT + (size_t)C_DIM * C_DIM;      // [4096,2304]
  unsigned short* vT     = qkv + (size_t)T_SEQ * C3;            // [768,4096]
  unsigned short* attnb  = vT + (size_t)C_DIM * T_SEQ;          // [4096,768]

  prep_fused<<<NB_CONV + NB_TQKV + NB_TPROJ, 256, 0, stream>>>(
      x, w_qkv, w_proj, xb, wqkvT, wprojT);

  gemm_bt_mfma<unsigned short><<<dim3(C3 / 128, T_SEQ / 128), 256, 0, stream>>>(
      xb, wqkvT, b_qkv, qkv, T_SEQ, C3, C_DIM);

  transpose_v_bf16<<<dim3(C_DIM / 32, T_SEQ / 32), 256, 0, stream>>>(qkv, vT);

  flash_attn_mfma6<<<T_SEQ / 64 * NH, 128, 0, stream>>>(qkv, vT, attnb);

  gemm_bt_mfma<float><<<dim3(C_DIM / 128, T_SEQ / 128), 256, 0, stream>>>(
      attnb, wprojT, b_proj, out, T_SEQ, C_DIM, C_DIM);
}

// Round 9
// 203.252 us; speedup vs baseline: 1.2771x; 1.1425x over previous
//
#include <hip/hip_runtime.h>
#include <hip/hip_bf16.h>

// CausalSelfAttention  B=1, T=4096, C=768, H=12, hd=64
// Round 9: flash v7 — 256-thr blocks (2x waves/SIMD vs v6) + globally
//   pre-permuted V^T so PV A-frags are single swizzled b128 LDS reads
//   (kills v6's 4-way b64 conflicts + packing movs). In-reg softmax and
//   reg-resident P kept from v6. GEMMs/preps otherwise unchanged.

#define T_SEQ 4096
#define C_DIM 768
#define C3    2304
#define NH    12
#define HD    64

typedef __attribute__((ext_vector_type(8))) short bf16x8;
typedef __attribute__((ext_vector_type(4))) float f32x4;

__device__ inline unsigned short f2bf(float f) {
  union { float f; unsigned u; } v; v.f = f;
  unsigned r = v.u + 0x7fff + ((v.u >> 16) & 1);  // RTNE
  return (unsigned short)(r >> 16);
}
__device__ inline unsigned short f2bf_trunc(float f) {
  union { float f; unsigned u; } v; v.f = f;
  return (unsigned short)(v.u >> 16);  // truncate: fine for P in [0,1]
}

__device__ inline void store_out(float v, float* p) { *p = v; }
__device__ inline void store_out(float v, unsigned short* p) { *p = f2bf(v); }

__device__ inline void gl2lds16(const void* g, void* l) {
  __builtin_amdgcn_global_load_lds(
      (const __attribute__((address_space(1))) unsigned int*)g,
      (__attribute__((address_space(3))) unsigned int*)l, 16, 0, 0);
}

#if __has_builtin(__builtin_amdgcn_exp2f)
#define EXP2F(x) __builtin_amdgcn_exp2f(x)
#else
#define EXP2F(x) exp2f(x)
#endif

// ---------------------------------------------------------------------------
// fused prep: conv x->bf16 | transpose w_qkv | transpose w_proj
// ---------------------------------------------------------------------------
#define NB_CONV  (T_SEQ * C_DIM / 2048)          // 1536
#define NB_TQKV  ((C3 / 32) * (C_DIM / 32))      // 1728
#define NB_TPROJ ((C_DIM / 32) * (C_DIM / 32))   // 576

__global__ __launch_bounds__(256) void prep_fused(
    const float* __restrict__ x, const float* __restrict__ w_qkv,
    const float* __restrict__ w_proj, unsigned short* __restrict__ xb,
    unsigned short* __restrict__ wqkvT, unsigned short* __restrict__ wprojT) {
  __shared__ float t[32][33];
  const int b = blockIdx.x;
  const int tid = threadIdx.x;

  if (b < NB_CONV) {
    int i = (b * 256 + tid) * 8;
    float4 v0 = *(const float4*)(x + i);
    float4 v1 = *(const float4*)(x + i + 4);
    unsigned short o[8] = {f2bf(v0.x), f2bf(v0.y), f2bf(v0.z), f2bf(v0.w),
                           f2bf(v1.x), f2bf(v1.y), f2bf(v1.z), f2bf(v1.w)};
    *(uint4*)(xb + i) = *(uint4*)o;
    return;
  }
  const float* in;
  unsigned short* outT;
  int R, Cc, bi;
  if (b < NB_CONV + NB_TQKV) {
    in = w_qkv; outT = wqkvT; R = C_DIM; Cc = C3; bi = b - NB_CONV;
  } else {
    in = w_proj; outT = wprojT; R = C_DIM; Cc = C_DIM; bi = b - NB_CONV - NB_TQKV;
  }
  const int tx = tid & 31, ty = tid >> 5;
  const int c0 = (bi % (Cc / 32)) * 32, r0 = (bi / (Cc / 32)) * 32;
#pragma unroll
  for (int i = 0; i < 4; ++i) {
    int r = ty + i * 8;
    t[r][tx] = in[(size_t)(r0 + r) * Cc + c0 + tx];
  }
  __syncthreads();
#pragma unroll
  for (int i = 0; i < 4; ++i) {
    int c = ty + i * 8;
    outT[(size_t)(c0 + c) * R + r0 + tx] = f2bf(t[tx][c]);
  }
}

// prep: permuted V^T — vTp[d][r0 + sigma(k&31)] = V[k][d].
// sigma maps position p -> phys pi(p) = (i<4 ? 4g+i : 16+4g+i-4), p=8g+i,
// so that LDS b128 reads of logical k-groups are contiguous.
__global__ __launch_bounds__(256) void transpose_v_perm(
    const unsigned short* __restrict__ qkv, unsigned short* __restrict__ vTp) {
  __shared__ unsigned short t[32][33];
  const int tx = threadIdx.x & 31, ty = threadIdx.x >> 5;
  const int c0 = blockIdx.x * 32;   // V d-column
  const int r0 = blockIdx.y * 32;   // sequence k (32-aligned)
#pragma unroll
  for (int i = 0; i < 4; ++i) {
    int r = ty + i * 8;
    t[r][tx] = qkv[(size_t)(r0 + r) * C3 + 2 * C_DIM + c0 + tx];
  }
  __syncthreads();
  // sigma(tx): inverse of pi within the 32-block
  const int pos = (tx < 16) ? (8 * (tx >> 2) + (tx & 3))
                            : (8 * ((tx - 16) >> 2) + 4 + ((tx - 16) & 3));
#pragma unroll
  for (int i = 0; i < 4; ++i) {
    int c = ty + i * 8;
    vTp[(size_t)(c0 + c) * T_SEQ + r0 + pos] = t[tx][c];
  }
}

// ---------------------------------------------------------------------------
// bf16 MFMA GEMM, B-transposed input (unchanged)
// ---------------------------------------------------------------------------
template <typename OutT>
__global__ __launch_bounds__(256) void gemm_bt_mfma(
    const unsigned short* __restrict__ A, const unsigned short* __restrict__ Bt,
    const float* __restrict__ bias, OutT* __restrict__ C,
    int M, int N, int K) {
  __shared__ unsigned short As[128 * 32];
  __shared__ unsigned short Bs[128 * 32];
  const int tid = threadIdx.x;
  const int wave = tid >> 6, lane = tid & 63;
  const int lo = lane & 15, g8 = lane >> 4;
  const int wm = wave >> 1, wn = wave & 1;
  const int bm = blockIdx.y * 128, bn = blockIdx.x * 128;
  const int lrow = lane >> 2;
  const int lcol = (lane & 3) * 8;

  f32x4 acc[4][4];
#pragma unroll
  for (int mt = 0; mt < 4; ++mt)
#pragma unroll
    for (int nt = 0; nt < 4; ++nt) acc[mt][nt] = (f32x4){0.f, 0.f, 0.f, 0.f};

  const unsigned short* Abase = A + (size_t)bm * K;
  const unsigned short* Bbase = Bt + (size_t)bn * K;

  for (int k0 = 0; k0 < K; k0 += 32) {
    __syncthreads();
#pragma unroll
    for (int c = 0; c < 2; ++c) {
      const int r = wave * 32 + c * 16;
      gl2lds16(Abase + (size_t)(r + lrow) * K + k0 + lcol, As + r * 32 + lane * 8);
      gl2lds16(Bbase + (size_t)(r + lrow) * K + k0 + lcol, Bs + r * 32 + lane * 8);
    }
    __syncthreads();

    bf16x8 a[4], b[4];
#pragma unroll
    for (int mt = 0; mt < 4; ++mt)
      a[mt] = *(const bf16x8*)(As + (wm * 64 + mt * 16 + lo) * 32 + g8 * 8);
#pragma unroll
    for (int nt = 0; nt < 4; ++nt)
      b[nt] = *(const bf16x8*)(Bs + (wn * 64 + nt * 16 + lo) * 32 + g8 * 8);
#pragma unroll
    for (int mt = 0; mt < 4; ++mt)
#pragma unroll
      for (int nt = 0; nt < 4; ++nt)
        acc[mt][nt] = __builtin_amdgcn_mfma_f32_16x16x32_bf16(a[mt], b[nt], acc[mt][nt], 0, 0, 0);
  }

#pragma unroll
  for (int nt = 0; nt < 4; ++nt) {
    const int n = bn + wn * 64 + nt * 16 + lo;
    const float bv = bias[n];
#pragma unroll
    for (int mt = 0; mt < 4; ++mt)
#pragma unroll
      for (int r = 0; r < 4; ++r) {
        const int m = bm + wm * 64 + mt * 16 + g8 * 4 + r;
        store_out(acc[mt][nt][r] + bv, &C[(size_t)m * N + n]);
      }
  }
}

// ---------------------------------------------------------------------------
// flash v7: St = K@Q^T, 256 threads (4 waves; wave w owns q-cols w*16..+15).
// K and permuted-V staged by lds-DMA into chunk-swizzled [64][64] buffers;
// all fragment reads are single b128, conflict-free. P stays in registers
// (C-frag -> B-operand, permutation baked into global V layout).
// ---------------------------------------------------------------------------
__global__ __launch_bounds__(256) void flash_attn_mfma7(
    const unsigned short* __restrict__ qkv,   // [T][2304] bf16
    const unsigned short* __restrict__ vTp,   // [768][T] bf16, k-permuted
    unsigned short* __restrict__ out) {       // [T][768] bf16
  __shared__ unsigned short Ks[2][64 * 64];
  __shared__ unsigned short Vs[2][64 * 64];

  const int qt = 63 - blockIdx.x / NH;  // LPT
  const int h = blockIdx.x % NH;
  const int q0 = qt * 64;
  const int tid = threadIdx.x;
  const int w = tid >> 6;
  const int lane = tid & 63;
  const int lo = lane & 15;
  const int g = lane >> 4;
  const int lo7 = lo & 7;
  const float qscale = 0.125f * 1.44269504f;  // 1/sqrt(64) * log2(e)

  const unsigned short* Kg = qkv + C_DIM + h * HD;          // row stride C3
  const unsigned short* Vg = vTp + (size_t)(h * HD) * T_SEQ; // row stride T_SEQ

  // DMA: 256 thr x 2 passes cover 64 rows x 8 chunks (chunk-swizzled dest)
  const int drow = tid >> 3;                    // 0..31
  const int dslot = (tid & 7) * 8;
  const int dsrc = ((tid & 7) ^ (drow & 7)) * 8;

  // Q B-frags direct from global (one-time)
  bf16x8 qb[2];
#pragma unroll
  for (int dh = 0; dh < 2; ++dh)
    qb[dh] = *(const bf16x8*)(
        qkv + (size_t)(q0 + w * 16 + lo) * C3 + h * HD + dh * 32 + g * 8);

  // prologue: DMA tile 0
#pragma unroll
  for (int p = 0; p < 2; ++p) {
    const int r = p * 32 + drow;
    gl2lds16(Kg + (size_t)r * C3 + dsrc, Ks[0] + r * 64 + dslot);
    gl2lds16(Vg + (size_t)r * T_SEQ + dsrc, Vs[0] + r * 64 + dslot);
  }
  __syncthreads();

  float m_i = -1e30f, l_i = 0.f;
  f32x4 o_acc[4];
#pragma unroll
  for (int dt = 0; dt < 4; ++dt) o_acc[dt] = (f32x4){0.f, 0.f, 0.f, 0.f};

  for (int t = 0; t <= qt; ++t) {
    const int cur = t & 1;
    if (t < qt) {
      const int k0n = (t + 1) * 64;
#pragma unroll
      for (int p = 0; p < 2; ++p) {
        const int r = p * 32 + drow;
        gl2lds16(Kg + (size_t)(k0n + r) * C3 + dsrc, Ks[cur ^ 1] + r * 64 + dslot);
        gl2lds16(Vg + (size_t)r * T_SEQ + k0n + dsrc, Vs[cur ^ 1] + r * 64 + dslot);
      }
    }

    // St = K @ Q^T  (C-frag: col=lo=q, row=g*4+r=k within mt*16)
    f32x4 st[4];
#pragma unroll
    for (int mt = 0; mt < 4; ++mt) st[mt] = (f32x4){0.f, 0.f, 0.f, 0.f};
#pragma unroll
    for (int mt = 0; mt < 4; ++mt)
#pragma unroll
      for (int dh = 0; dh < 2; ++dh) {
        bf16x8 a = *(const bf16x8*)(
            Ks[cur] + (mt * 16 + lo) * 64 + (((dh * 4 + g) ^ lo7) * 8));
        st[mt] = __builtin_amdgcn_mfma_f32_16x16x32_bf16(a, qb[dh], st[mt], 0, 0, 0);
      }

    // softmax (raw domain; scale folded into exp2)
    if (t == qt) {
      const int qloc = w * 16 + lo;
#pragma unroll
      for (int mt = 0; mt < 4; ++mt)
#pragma unroll
        for (int r = 0; r < 4; ++r)
          if (mt * 16 + g * 4 + r > qloc) st[mt][r] = -1e30f;
    }
    float mx = -1e30f;
#pragma unroll
    for (int mt = 0; mt < 4; ++mt)
#pragma unroll
      for (int r = 0; r < 4; ++r) mx = fmaxf(mx, st[mt][r]);
    mx = fmaxf(mx, __shfl_xor(mx, 16));
    mx = fmaxf(mx, __shfl_xor(mx, 32));
    const float mnew = fmaxf(m_i, mx);
    const float alpha = EXP2F((m_i - mnew) * qscale);
    m_i = mnew;
    const float ms = mnew * qscale;
    float e[4][4];
    float lsum = 0.f;
#pragma unroll
    for (int mt = 0; mt < 4; ++mt)
#pragma unroll
      for (int r = 0; r < 4; ++r) {
        float v = EXP2F(__builtin_fmaf(st[mt][r], qscale, -ms));
        e[mt][r] = v;
        lsum += v;
      }
    lsum += __shfl_xor(lsum, 16);
    lsum += __shfl_xor(lsum, 32);
    // pack P^T B-frags: logical k g*8+i -> phys kh*32 + (i<4?4g+i:16+4g+i-4)
    bf16x8 pt[2];
#pragma unroll
    for (int kh = 0; kh < 2; ++kh) {
#pragma unroll
      for (int j = 0; j < 4; ++j) {
        pt[kh][j] = (short)f2bf_trunc(e[kh * 2][j]);
        pt[kh][4 + j] = (short)f2bf_trunc(e[kh * 2 + 1][j]);
      }
    }
    if (__any(alpha != 1.0f)) {
      l_i *= alpha;
#pragma unroll
      for (int dt = 0; dt < 4; ++dt)
#pragma unroll
        for (int r = 0; r < 4; ++r) o_acc[dt][r] *= alpha;
    }
    l_i += lsum;

    // O^T += V^T @ P^T (single swizzled b128 per A-frag, pre-permuted layout)
#pragma unroll
    for (int dt = 0; dt < 4; ++dt)
#pragma unroll
      for (int kh = 0; kh < 2; ++kh) {
        bf16x8 av = *(const bf16x8*)(
            Vs[cur] + (dt * 16 + lo) * 64 + (((kh * 4 + g) ^ lo7) * 8));
        o_acc[dt] = __builtin_amdgcn_mfma_f32_16x16x32_bf16(av, pt[kh], o_acc[dt], 0, 0, 0);
      }

    __syncthreads();  // drain prefetch DMAs + release buffer cur
  }

  // epilogue: O^T frags -> Ks[0] (dead, swizzled, wave-local) -> coalesced out
  const float inv = 1.0f / l_i;
#pragma unroll
  for (int dt = 0; dt < 4; ++dt) {
    const int chunk = (dt * 2 + (g >> 1)) ^ lo7;
#pragma unroll
    for (int r = 0; r < 4; ++r)
      Ks[0][(w * 16 + lo) * 64 + chunk * 8 + (g & 1) * 4 + r] =
          f2bf(o_acc[dt][r] * inv);
  }
  // same-wave readback (rows disjoint per wave; lgkmcnt orders within wave)
#pragma unroll
  for (int i = 0; i < 2; ++i) {
    const int row = w * 16 + i * 8 + (lane >> 3);
    bf16x8 val = *(const bf16x8*)(Ks[0] + row * 64 + (((lane & 7) ^ (row & 7)) * 8));
    *(bf16x8*)(out + (size_t)(q0 + row) * C_DIM + h * HD + (lane & 7) * 8) = val;
  }
}

// ---------------------------------------------------------------------------
extern "C" void kernel_launch(void* const* d_in, const int* in_sizes, int n_in,
                              void* d_out, int out_size, void* d_ws, size_t ws_size,
                              hipStream_t stream) {
  const float* x      = (const float*)d_in[0];
  const float* w_qkv  = (const float*)d_in[1];
  const float* b_qkv  = (const float*)d_in[2];
  const float* w_proj = (const float*)d_in[3];
  const float* b_proj = (const float*)d_in[4];
  float* out = (float*)d_out;

  unsigned short* xb     = (unsigned short*)d_ws;               // [4096,768]
  unsigned short* wqkvT  = xb + (size_t)T_SEQ * C_DIM;          // [2304,768]
  unsigned short* wprojT = wqkvT + (size_t)C3 * C_DIM;          // [768,768]
  unsigned short* qkv    = wprojT + (size_t)C_DIM * C_DIM;      // [4096,2304]
  unsigned short* vTp    = qkv + (size_t)T_SEQ * C3;            // [768,4096]
  unsigned short* attnb  = vTp + (size_t)C_DIM * T_SEQ;         // [4096,768]

  prep_fused<<<NB_CONV + NB_TQKV + NB_TPROJ, 256, 0, stream>>>(
      x, w_qkv, w_proj, xb, wqkvT, wprojT);

  gemm_bt_mfma<unsigned short><<<dim3(C3 / 128, T_SEQ / 128), 256, 0, stream>>>(
      xb, wqkvT, b_qkv, qkv, T_SEQ, C3, C_DIM);

  transpose_v_perm<<<dim3(C_DIM / 32, T_SEQ / 32), 256, 0, stream>>>(qkv, vTp);

  flash_attn_mfma7<<<T_SEQ / 64 * NH, 256, 0, stream>>>(qkv, vTp, attnb);

  gemm_bt_mfma<float><<<dim3(C_DIM / 128, T_SEQ / 128), 256, 0, stream>>>(
      attnb, wprojT, b_proj, out, T_SEQ, C_DIM, C_DIM);
}